// Round 3
// baseline (175.557 us; speedup 1.0000x reference)
//
#include <hip/hip_runtime.h>

#define N_POS 4096
#define BH 16  // B * HEADS

// ---------------- K1: qkv projection ----------------
// qkv[b][o][i] = sum_c w_qkv[o][c] * x[b][c][i]
// q is pre-scaled by DIM_HEAD^-0.5 * log2(e) so K2 can use exp2f directly.
__global__ __launch_bounds__(256) void qkv_proj(const float* __restrict__ x,
                                                const float* __restrict__ w_qkv,
                                                float* __restrict__ qbuf,
                                                float* __restrict__ kvbuf) {
    int blk = blockIdx.x;
    int ic   = blk & 15;
    int rest = blk >> 4;
    int o = rest % 48;
    int b = rest / 48;
    int i = ic * 256 + threadIdx.x;
    const float* wrow = w_qkv + o * 64;
    const float* xb   = x + ((size_t)b * 64) * N_POS + i;
    float acc = 0.f;
#pragma unroll
    for (int c = 0; c < 64; ++c)
        acc = fmaf(wrow[c], xb[(size_t)c * N_POS], acc);

    if (o < 16) {
        int h = o >> 2, d = o & 3;
        // fold softmax scale (0.5) and log2(e) for exp2-based softmax
        qbuf[(((size_t)(b * 4 + h)) * N_POS + i) * 4 + d] = acc * (0.5f * 1.44269504088896f);
    } else if (o < 32) {
        int oo = o - 16, h = oo >> 2, d = oo & 3;
        kvbuf[(((size_t)(b * 4 + h)) * N_POS + i) * 8 + d] = acc;
    } else {
        int oo = o - 32, h = oo >> 2, d = oo & 3;
        kvbuf[(((size_t)(b * 4 + h)) * N_POS + i) * 8 + 4 + d] = acc;
    }
}

// ---------------- K2: flash attention partials (max-free softmax, exp2) ----------------
// grid = 16 bh * 4 qtiles * JS jslices, 256 threads, RQ=4 q-positions/thread.
template<int JS>
__global__ __launch_bounds__(256) void attn_partial(const float* __restrict__ qbuf,
                                                    const float* __restrict__ kvbuf,
                                                    float4* __restrict__ pacc,
                                                    float* __restrict__ pl) {
    constexpr int JLEN = N_POS / JS;          // j positions per block
    __shared__ float4 kvl[JLEN * 2];          // JLEN * (k4 + v4)
    int blk = blockIdx.x;
    int js = blk % JS;
    int qt = (blk / JS) & 3;
    int bh = blk / (JS * 4);

    const float4* src = (const float4*)kvbuf + ((size_t)bh * N_POS + js * JLEN) * 2;
#pragma unroll
    for (int r = 0; r < (JLEN * 2) / 256; ++r)
        kvl[threadIdx.x + r * 256] = src[threadIdx.x + r * 256];
    __syncthreads();

    const float4* q4 = (const float4*)qbuf + (size_t)bh * N_POS + qt * 1024 + threadIdx.x;
    float4 q[4], acc[4];
    float  l[4];
#pragma unroll
    for (int r = 0; r < 4; ++r) {
        q[r] = q4[r * 256];
        acc[r] = make_float4(0.f, 0.f, 0.f, 0.f);
        l[r] = 0.f;
    }

#pragma unroll 4
    for (int j = 0; j < JLEN; ++j) {
        float4 k = kvl[2 * j];
        float4 v = kvl[2 * j + 1];
#pragma unroll
        for (int r = 0; r < 4; ++r) {
            float s = fmaf(q[r].w, k.w, fmaf(q[r].z, k.z, fmaf(q[r].y, k.y, q[r].x * k.x)));
            float p = exp2f(s);   // v_exp_f32 directly (log2e folded into q)
            l[r] += p;
            acc[r].x = fmaf(p, v.x, acc[r].x);
            acc[r].y = fmaf(p, v.y, acc[r].y);
            acc[r].z = fmaf(p, v.z, acc[r].z);
            acc[r].w = fmaf(p, v.w, acc[r].w);
        }
    }

    size_t base = (size_t)js * (BH * N_POS) + (size_t)bh * N_POS + qt * 1024 + threadIdx.x;
#pragma unroll
    for (int r = 0; r < 4; ++r) {
        pacc[base + r * 256] = acc[r];
        pl[base + r * 256]   = l[r];
    }
}

// ---------------- K3: combine partials + output projection + bias ----------------
template<int JS>
__global__ __launch_bounds__(256) void combine_proj(const float4* __restrict__ pacc,
                                                    const float* __restrict__ pl,
                                                    const float* __restrict__ w_out,
                                                    const float* __restrict__ b_out,
                                                    float* __restrict__ y) {
    int gi = blockIdx.x * 256 + threadIdx.x;  // b*4096 + i
    int b = gi >> 12;
    int i = gi & 4095;

    float o[16];
#pragma unroll
    for (int h = 0; h < 4; ++h) {
        float ax = 0.f, ay = 0.f, az = 0.f, aw = 0.f, l = 0.f;
#pragma unroll
        for (int js = 0; js < JS; ++js) {
            size_t idx = (size_t)js * (BH * N_POS) + (size_t)(b * 4 + h) * N_POS + i;
            float4 t = pacc[idx];
            ax += t.x; ay += t.y; az += t.z; aw += t.w;
            l += pl[idx];
        }
        float inv = 1.0f / l;
        o[h * 4 + 0] = ax * inv;
        o[h * 4 + 1] = ay * inv;
        o[h * 4 + 2] = az * inv;
        o[h * 4 + 3] = aw * inv;
    }

    float* yb = y + (size_t)b * 64 * N_POS + i;
#pragma unroll
    for (int c = 0; c < 64; ++c) {
        const float* wr = w_out + c * 16;
        float s = b_out[c];
#pragma unroll
        for (int t = 0; t < 16; ++t) s = fmaf(wr[t], o[t], s);
        yb[(size_t)c * N_POS] = s;
    }
}

extern "C" void kernel_launch(void* const* d_in, const int* in_sizes, int n_in,
                              void* d_out, int out_size, void* d_ws, size_t ws_size,
                              hipStream_t stream) {
    const float* x     = (const float*)d_in[0];
    const float* w_qkv = (const float*)d_in[1];
    const float* w_out = (const float*)d_in[2];
    const float* b_out = (const float*)d_in[3];
    float* y = (float*)d_out;

    // workspace layout (floats):
    // qbuf: [16][4096][4]            = 262144
    // kvbuf:[16][4096][8]            = 524288
    // pacc: [JS][16][4096] float4    = JS*16*4096*4 floats
    // pl:   [JS][16][4096]           = JS*16*4096
    float* w = (float*)d_ws;
    float*  qbuf  = w;
    float*  kvbuf = w + 262144;
    float4* pacc  = (float4*)(w + 262144 + 524288);

    size_t need16 = ((size_t)262144 + 524288 + 16UL * BH * N_POS * 5) * 4;

    if (ws_size >= need16) {
        constexpr int JS = 16;
        float* pl = w + 262144 + 524288 + (size_t)JS * BH * N_POS * 4;
        qkv_proj<<<4 * 48 * 16, 256, 0, stream>>>(x, w_qkv, qbuf, kvbuf);
        attn_partial<JS><<<BH * 4 * JS, 256, 0, stream>>>(qbuf, kvbuf, pacc, pl);
        combine_proj<JS><<<64, 256, 0, stream>>>(pacc, pl, w_out, b_out, y);
    } else {
        constexpr int JS = 8;
        float* pl = w + 262144 + 524288 + (size_t)JS * BH * N_POS * 4;
        qkv_proj<<<4 * 48 * 16, 256, 0, stream>>>(x, w_qkv, qbuf, kvbuf);
        attn_partial<JS><<<BH * 4 * JS, 256, 0, stream>>>(qbuf, kvbuf, pacc, pl);
        combine_proj<JS><<<64, 256, 0, stream>>>(pacc, pl, w_out, b_out, y);
    }
}

// Round 5
// 139.450 us; speedup vs baseline: 1.2589x; 1.2589x over previous
//
#include <hip/hip_runtime.h>

#define N_POS 4096
#define BH 16  // B * HEADS

#if __has_builtin(__builtin_amdgcn_exp2f)
#define QSCALE (0.5f * 1.44269504088896f)   // fold dim^-0.5 and log2(e) into q
__device__ __forceinline__ float fast_exp(float x) { return __builtin_amdgcn_exp2f(x); }
#else
#define QSCALE (0.5f)
__device__ __forceinline__ float fast_exp(float x) { return __expf(x); }
#endif

// ---------------- K1: qkv projection ----------------
// qkv[b][o][i] = sum_c w_qkv[o][c] * x[b][c][i]; w row wave-uniform -> scalar loads.
__global__ __launch_bounds__(256) void qkv_proj(const float* __restrict__ x,
                                                const float* __restrict__ w_qkv,
                                                float* __restrict__ qbuf,
                                                float* __restrict__ kvbuf) {
    int blk = blockIdx.x;
    int ic   = blk & 15;
    int rest = blk >> 4;
    int o = rest % 48;
    int b = rest / 48;
    int i = ic * 256 + threadIdx.x;
    const float* wrow = w_qkv + o * 64;
    const float* xb   = x + ((size_t)b * 64) * N_POS + i;
    float acc = 0.f;
#pragma unroll
    for (int c = 0; c < 64; ++c)
        acc = fmaf(wrow[c], xb[(size_t)c * N_POS], acc);

    if (o < 16) {
        int h = o >> 2, d = o & 3;
        qbuf[(((size_t)(b * 4 + h)) * N_POS + i) * 4 + d] = acc * QSCALE;
    } else if (o < 32) {
        int oo = o - 16, h = oo >> 2, d = oo & 3;
        kvbuf[(((size_t)(b * 4 + h)) * N_POS + i) * 8 + d] = acc;
    } else {
        int oo = o - 32, h = oo >> 2, d = oo & 3;
        kvbuf[(((size_t)(b * 4 + h)) * N_POS + i) * 8 + 4 + d] = acc;
    }
}

// ---------------- K2: flash attention partials (max-free softmax, raw v_exp) ----
// grid = 16 bh * 4 qtiles * JS jslices, 256 threads, RQ=4 q-positions/thread.
// k/v register double-buffered; kvl padded +2 so the last prefetch is safe.
template<int JS>
__global__ __launch_bounds__(256, 4) void attn_partial(const float* __restrict__ qbuf,
                                                       const float* __restrict__ kvbuf,
                                                       float4* __restrict__ pacc,
                                                       float* __restrict__ pl) {
    constexpr int JLEN = N_POS / JS;
    __shared__ float4 kvl[JLEN * 2 + 2];
    int blk = blockIdx.x;
    int js = blk % JS;
    int qt = (blk / JS) & 3;
    int bh = blk / (JS * 4);

    const float4* src = (const float4*)kvbuf + ((size_t)bh * N_POS + js * JLEN) * 2;
#pragma unroll
    for (int r = 0; r < (JLEN * 2) / 256; ++r)
        kvl[threadIdx.x + r * 256] = src[threadIdx.x + r * 256];
    __syncthreads();

    const float4* q4 = (const float4*)qbuf + (size_t)bh * N_POS + qt * 1024 + threadIdx.x;
    float4 q[4], acc[4];
    float  l[4];
#pragma unroll
    for (int r = 0; r < 4; ++r) {
        q[r] = q4[r * 256];
        acc[r] = make_float4(0.f, 0.f, 0.f, 0.f);
        l[r] = 0.f;
    }

    float4 k0 = kvl[0], v0 = kvl[1];
#pragma unroll 4
    for (int j = 0; j < JLEN; ++j) {
        float4 k1 = kvl[2 * j + 2];
        float4 v1 = kvl[2 * j + 3];
#pragma unroll
        for (int r = 0; r < 4; ++r) {
            float sa = fmaf(q[r].y, k0.y, q[r].x * k0.x);
            float sb = fmaf(q[r].w, k0.w, q[r].z * k0.z);
            float p = fast_exp(sa + sb);
            l[r] += p;
            acc[r].x = fmaf(p, v0.x, acc[r].x);
            acc[r].y = fmaf(p, v0.y, acc[r].y);
            acc[r].z = fmaf(p, v0.z, acc[r].z);
            acc[r].w = fmaf(p, v0.w, acc[r].w);
        }
        k0 = k1; v0 = v1;
    }

    size_t base = (size_t)js * (BH * N_POS) + (size_t)bh * N_POS + qt * 1024 + threadIdx.x;
#pragma unroll
    for (int r = 0; r < 4; ++r) {
        pacc[base + r * 256] = acc[r];
        pl[base + r * 256]   = l[r];
    }
}

// ---------------- K3a: combine partials -> normalized out [bh][i] float4 -------
template<int JS>
__global__ __launch_bounds__(256) void combine_partials(const float4* __restrict__ pacc,
                                                        const float* __restrict__ pl,
                                                        float4* __restrict__ obuf) {
    int t = blockIdx.x * 256 + threadIdx.x;  // bh*4096 + i, 65536 threads / 256 blocks
    float sx = 0.f, sy = 0.f, sz = 0.f, sw = 0.f, l = 0.f;
#pragma unroll
    for (int js = 0; js < JS; ++js) {
        size_t idx = (size_t)js * (BH * N_POS) + t;
        float4 a = pacc[idx];
        sx += a.x; sy += a.y; sz += a.z; sw += a.w;
        l += pl[idx];
    }
    float inv = 1.0f / l;
    obuf[t] = make_float4(sx * inv, sy * inv, sz * inv, sw * inv);
}

// ---------------- K3b: output projection + bias --------------------------------
// thread = (b, c-quarter, i): 65536 threads / 256 blocks, 16 channels each.
__global__ __launch_bounds__(256) void out_proj(const float4* __restrict__ obuf,
                                                const float* __restrict__ w_out,
                                                const float* __restrict__ b_out,
                                                float* __restrict__ y) {
    int t = blockIdx.x * 256 + threadIdx.x;
    int b  = t >> 14;
    int cq = (t >> 12) & 3;
    int i  = t & 4095;

    float4 o0 = obuf[(b * 4 + 0) * N_POS + i];
    float4 o1 = obuf[(b * 4 + 1) * N_POS + i];
    float4 o2 = obuf[(b * 4 + 2) * N_POS + i];
    float4 o3 = obuf[(b * 4 + 3) * N_POS + i];
    float of[16] = {o0.x, o0.y, o0.z, o0.w, o1.x, o1.y, o1.z, o1.w,
                    o2.x, o2.y, o2.z, o2.w, o3.x, o3.y, o3.z, o3.w};

    float* yb = y + ((size_t)b * 64 + cq * 16) * N_POS + i;
#pragma unroll
    for (int cc = 0; cc < 16; ++cc) {
        const float* wr = w_out + (cq * 16 + cc) * 16;  // wave-uniform row
        float s = b_out[cq * 16 + cc];
#pragma unroll
        for (int u = 0; u < 16; ++u) s = fmaf(wr[u], of[u], s);
        yb[(size_t)cc * N_POS] = s;
    }
}

extern "C" void kernel_launch(void* const* d_in, const int* in_sizes, int n_in,
                              void* d_out, int out_size, void* d_ws, size_t ws_size,
                              hipStream_t stream) {
    const float* x     = (const float*)d_in[0];
    const float* w_qkv = (const float*)d_in[1];
    const float* w_out = (const float*)d_in[2];
    const float* b_out = (const float*)d_in[3];
    float* y = (float*)d_out;

    // workspace (floats): qbuf 262144 | kvbuf 524288 | pacc JS*65536*4 | pl JS*65536 | obuf 262144
    float* w = (float*)d_ws;
    float*  qbuf  = w;
    float*  kvbuf = w + 262144;
    float4* pacc  = (float4*)(w + 786432);

    size_t need16 = ((size_t)786432 + 16UL * 65536 * 5 + 262144) * 4;

    if (ws_size >= need16) {
        constexpr int JS = 16;
        float*  pl   = w + 786432 + (size_t)JS * 65536 * 4;
        float4* obuf = (float4*)(w + 786432 + (size_t)JS * 65536 * 5);
        qkv_proj<<<4 * 48 * 16, 256, 0, stream>>>(x, w_qkv, qbuf, kvbuf);
        attn_partial<JS><<<BH * 4 * JS, 256, 0, stream>>>(qbuf, kvbuf, pacc, pl);
        combine_partials<JS><<<256, 256, 0, stream>>>(pacc, pl, obuf);
        out_proj<<<256, 256, 0, stream>>>(obuf, w_out, b_out, y);
    } else {
        constexpr int JS = 8;
        float*  pl   = w + 786432 + (size_t)JS * 65536 * 4;
        float4* obuf = (float4*)(w + 786432 + (size_t)JS * 65536 * 5);
        qkv_proj<<<4 * 48 * 16, 256, 0, stream>>>(x, w_qkv, qbuf, kvbuf);
        attn_partial<JS><<<BH * 4 * JS, 256, 0, stream>>>(qbuf, kvbuf, pacc, pl);
        combine_partials<JS><<<256, 256, 0, stream>>>(pacc, pl, obuf);
        out_proj<<<256, 256, 0, stream>>>(obuf, w_out, b_out, y);
    }
}

// Round 6
// 92.436 us; speedup vs baseline: 1.8992x; 1.5086x over previous
//
#include <hip/hip_runtime.h>
#include <hip/hip_bf16.h>

#define N_POS 4096
#define BH 16  // B * HEADS

typedef float f32x16 __attribute__((ext_vector_type(16)));
typedef short bf16x8 __attribute__((ext_vector_type(8)));

// fold attn scale (dim^-0.5 = 0.5) and log2(e) into q at pack time
#define QSCALE (0.5f * 1.44269504088896f)

__device__ __forceinline__ float fexp2(float x) {
#if __has_builtin(__builtin_amdgcn_exp2f)
    return __builtin_amdgcn_exp2f(x);
#else
    return exp2f(x);
#endif
}

__device__ __forceinline__ unsigned int bfbits(float f) {
    __hip_bfloat16 h = __float2bfloat16(f);
    return (unsigned int)*reinterpret_cast<unsigned short*>(&h);
}
__device__ __forceinline__ float bff32(unsigned int u) {
    unsigned int w = u << 16;
    float f;
    __builtin_memcpy(&f, &w, 4);
    return f;
}
__device__ __forceinline__ unsigned int pk2(unsigned int lo, unsigned int hi) {
    return lo | (hi << 16);
}

// ---------------- K1: qkv projection + MFMA fragment packing ----------------
// thread = (b, h, i). Computes q,k,v (d=4 each), then writes:
//  qfrag[bh][it][half][i&31]  : B-frag for QK  (half0=[qhi,qlo], half1=[qhi,0])
//  kfrag[bh][jt][half][j&31]  : A-frag for QK  (half0=[khi,khi], half1=[klo,0])
//   -> one 32x32x16 MFMA computes qhi*khi + qlo*khi + qhi*klo  (compensated dot)
//  vfrag[bh][step][vh][col][8]: B-frag for PV, col4 = ones (free l = sum(p))
__global__ __launch_bounds__(256) void qkv_pack(const float* __restrict__ x,
                                                const float* __restrict__ w_qkv,
                                                uint4* __restrict__ qfrag,
                                                uint4* __restrict__ kfrag,
                                                unsigned short* __restrict__ vfrag) {
    int blk = blockIdx.x;        // 16 bh * 16 chunks
    int chunk = blk & 15;
    int bh = blk >> 4;
    int b = bh >> 2, h = bh & 3;
    int i = chunk * 256 + threadIdx.x;

    const float* xb = x + ((size_t)b * 64) * N_POS + i;
    const float* wq = w_qkv + (h * 4) * 64;          // wave-uniform rows
    const float* wk = w_qkv + (16 + h * 4) * 64;
    const float* wv = w_qkv + (32 + h * 4) * 64;

    float aq[4] = {0, 0, 0, 0}, ak[4] = {0, 0, 0, 0}, av[4] = {0, 0, 0, 0};
#pragma unroll 8
    for (int c = 0; c < 64; ++c) {
        float xv = xb[(size_t)c * N_POS];
#pragma unroll
        for (int d = 0; d < 4; ++d) {
            aq[d] = fmaf(wq[d * 64 + c], xv, aq[d]);
            ak[d] = fmaf(wk[d * 64 + c], xv, ak[d]);
            av[d] = fmaf(wv[d * 64 + c], xv, av[d]);
        }
    }

    unsigned int qh[4], ql[4], kh[4], kl[4];
#pragma unroll
    for (int d = 0; d < 4; ++d) {
        float qs = aq[d] * QSCALE;
        qh[d] = bfbits(qs);
        ql[d] = bfbits(qs - bff32(qh[d]));
        kh[d] = bfbits(ak[d]);
        kl[d] = bfbits(ak[d] - bff32(kh[d]));
    }

    int it = i >> 5, il = i & 31;
    size_t base = ((size_t)(bh * 128 + it) * 2) * 32 + il;
    qfrag[base]      = make_uint4(pk2(qh[0], qh[1]), pk2(qh[2], qh[3]),
                                  pk2(ql[0], ql[1]), pk2(ql[2], ql[3]));
    qfrag[base + 32] = make_uint4(pk2(qh[0], qh[1]), pk2(qh[2], qh[3]), 0u, 0u);
    kfrag[base]      = make_uint4(pk2(kh[0], kh[1]), pk2(kh[2], kh[3]),
                                  pk2(kh[0], kh[1]), pk2(kh[2], kh[3]));
    kfrag[base + 32] = make_uint4(pk2(kl[0], kl[1]), pk2(kl[2], kl[3]), 0u, 0u);

    // v transpose-pack: element (j&7) of entry [step=j>>4][vh=(j>>3)&1][col=d]
    int step = i >> 4, vh = (i >> 3) & 1, e = i & 7;
    size_t ventry = ((size_t)(bh * 256 + step) * 2 + vh) * 5;
#pragma unroll
    for (int d = 0; d < 4; ++d)
        vfrag[(ventry + d) * 8 + e] = (unsigned short)bfbits(av[d]);
    if (e == 0)  // ones column -> PV MFMA also produces l = sum_j p
        reinterpret_cast<uint4*>(vfrag)[ventry + 4] =
            make_uint4(0x3F803F80u, 0x3F803F80u, 0x3F803F80u, 0x3F803F80u);
}

// ---------------- K2: MFMA flash attention (max-free softmax) ----------------
// wave = one 32-row i-tile, iterates all 4096 j. No LDS, no partial combine.
// Per 32-j tile: 1 QK mfma -> 16 exp -> 8 cvt_pk + 4 permlane32_swap -> 2 PV mfma.
__global__ __launch_bounds__(256, 2) void attn_mfma(const uint4* __restrict__ qfrag,
                                                    const uint4* __restrict__ kfrag,
                                                    const uint4* __restrict__ vfrag,
                                                    float* __restrict__ obuf) {
    int wave = threadIdx.x >> 6;
    int lane = threadIdx.x & 63;
    int half = lane >> 5, c = lane & 31;
    int blk = blockIdx.x;        // 16 bh * 32 it-groups
    int bh = blk >> 5;
    int it = (blk & 31) * 4 + wave;

    uint4 qf_u = qfrag[((size_t)(bh * 128 + it) * 2 + half) * 32 + c];
    bf16x8 qf = __builtin_bit_cast(bf16x8, qf_u);

    const uint4* kptr = kfrag + (size_t)bh * 128 * 64 + (size_t)half * 32 + c;
    int vcol = c < 4 ? c : 4;    // cols >4 read the ones column (result ignored)
    const uint4* vptr = vfrag + (size_t)bh * 2560 + half * 5 + vcol;

    f32x16 acc, zc;
#pragma unroll
    for (int r = 0; r < 16; ++r) { acc[r] = 0.f; zc[r] = 0.f; }

#pragma unroll 2
    for (int jt = 0; jt < 128; ++jt) {
        bf16x8 kf = __builtin_bit_cast(bf16x8, kptr[jt * 64]);
        // S^T tile [j=32 rows, i=32 cols], compensated bf16 dot, log2e folded
        f32x16 s = __builtin_amdgcn_mfma_f32_32x32x16_bf16(kf, qf, zc, 0, 0, 0);
        unsigned int t[8];
#pragma unroll
        for (int eo = 0; eo < 8; ++eo) {
            float plo = fexp2(s[2 * eo]);
            float phi = fexp2(s[2 * eo + 1]);
            unsigned int r_;
            asm("v_cvt_pk_bf16_f32 %0, %1, %2" : "=v"(r_) : "v"(plo), "v"(phi));
            t[eo] = r_;
        }
        // D-layout -> PV A-frag: swap upper half of t[a] with lower half of t[a+2]
        asm("v_permlane32_swap_b32 %0, %1" : "+v"(t[0]), "+v"(t[2]));
        asm("v_permlane32_swap_b32 %0, %1" : "+v"(t[1]), "+v"(t[3]));
        asm("v_permlane32_swap_b32 %0, %1" : "+v"(t[4]), "+v"(t[6]));
        asm("v_permlane32_swap_b32 %0, %1" : "+v"(t[5]), "+v"(t[7]));
        bf16x8 pa0 = __builtin_bit_cast(bf16x8, make_uint4(t[0], t[1], t[2], t[3]));
        bf16x8 pa1 = __builtin_bit_cast(bf16x8, make_uint4(t[4], t[5], t[6], t[7]));
        bf16x8 v0 = __builtin_bit_cast(bf16x8, vptr[(2 * jt) * 10]);
        bf16x8 v1 = __builtin_bit_cast(bf16x8, vptr[(2 * jt + 1) * 10]);
        acc = __builtin_amdgcn_mfma_f32_32x32x16_bf16(pa0, v0, acc, 0, 0, 0);
        acc = __builtin_amdgcn_mfma_f32_32x32x16_bf16(pa1, v1, acc, 0, 0, 0);
    }

    // epilogue: cols 0-3 = sum p*v, col 4 = l = sum p -> normalize, store
    int src = (lane & 32) | 4;
#pragma unroll
    for (int r = 0; r < 16; ++r) {
        float l = __shfl(acc[r], src, 64);
        float o = acc[r] / l;
        if (c < 4) {
            int row = (r & 3) + 8 * (r >> 2) + 4 * half;
            obuf[(((size_t)bh * N_POS) + it * 32 + row) * 4 + c] = o;
        }
    }
}

// ---------------- K3: output projection + bias --------------------------------
__global__ __launch_bounds__(256) void out_proj(const float4* __restrict__ obuf,
                                                const float* __restrict__ w_out,
                                                const float* __restrict__ b_out,
                                                float* __restrict__ y) {
    int t = blockIdx.x * 256 + threadIdx.x;
    int b  = t >> 14;
    int cq = (t >> 12) & 3;
    int i  = t & 4095;

    float4 o0 = obuf[(b * 4 + 0) * N_POS + i];
    float4 o1 = obuf[(b * 4 + 1) * N_POS + i];
    float4 o2 = obuf[(b * 4 + 2) * N_POS + i];
    float4 o3 = obuf[(b * 4 + 3) * N_POS + i];
    float of[16] = {o0.x, o0.y, o0.z, o0.w, o1.x, o1.y, o1.z, o1.w,
                    o2.x, o2.y, o2.z, o2.w, o3.x, o3.y, o3.z, o3.w};

    float* yb = y + ((size_t)b * 64 + cq * 16) * N_POS + i;
#pragma unroll
    for (int cc = 0; cc < 16; ++cc) {
        const float* wr = w_out + (cq * 16 + cc) * 16;  // wave-uniform row
        float s = b_out[cq * 16 + cc];
#pragma unroll
        for (int u = 0; u < 16; ++u) s = fmaf(wr[u], of[u], s);
        yb[(size_t)cc * N_POS] = s;
    }
}

extern "C" void kernel_launch(void* const* d_in, const int* in_sizes, int n_in,
                              void* d_out, int out_size, void* d_ws, size_t ws_size,
                              hipStream_t stream) {
    const float* x     = (const float*)d_in[0];
    const float* w_qkv = (const float*)d_in[1];
    const float* w_out = (const float*)d_in[2];
    const float* b_out = (const float*)d_in[3];
    float* y = (float*)d_out;

    // workspace (bytes): qfrag 2MB | kfrag 2MB | vfrag 640KB | obuf 1MB  (~5.9MB)
    char* w = (char*)d_ws;
    uint4*          qfrag = (uint4*)(w);
    uint4*          kfrag = (uint4*)(w + 2097152);
    unsigned short* vfrag = (unsigned short*)(w + 4194304);
    float*          obuf  = (float*)(w + 4849664);

    qkv_pack<<<256, 256, 0, stream>>>(x, w_qkv, qfrag, kfrag, vfrag);
    attn_mfma<<<512, 256, 0, stream>>>(qfrag, kfrag, (const uint4*)vfrag, obuf);
    out_proj<<<256, 256, 0, stream>>>((const float4*)obuf, w_out, b_out, y);
}

// Round 7
// 54.526 us; speedup vs baseline: 3.2197x; 1.6952x over previous
//
#include <hip/hip_runtime.h>
#include <hip/hip_bf16.h>

#define N_POS 4096
#define BH 16  // B * HEADS
#define JS 4   // j-slices (partials combine linearly: max-free softmax)

typedef float f32x16 __attribute__((ext_vector_type(16)));
typedef short bf16x8 __attribute__((ext_vector_type(8)));

// fold attn scale (dim^-0.5 = 0.5) and log2(e) into q at pack time
#define QSCALE (0.5f * 1.44269504088896f)

__device__ __forceinline__ float fexp2(float x) {
#if __has_builtin(__builtin_amdgcn_exp2f)
    return __builtin_amdgcn_exp2f(x);
#else
    return exp2f(x);
#endif
}

__device__ __forceinline__ unsigned int bfbits(float f) {
    __hip_bfloat16 h = __float2bfloat16(f);
    return (unsigned int)*reinterpret_cast<unsigned short*>(&h);
}
__device__ __forceinline__ float bff32(unsigned int u) {
    unsigned int w = u << 16;
    float f;
    __builtin_memcpy(&f, &w, 4);
    return f;
}
__device__ __forceinline__ unsigned int pk2(unsigned int lo, unsigned int hi) {
    return lo | (hi << 16);
}

// ---------------- K1: qkv projection + MFMA fragment packing ----------------
//  qfrag[bh][it][half][i&31]  : B-frag for QK  (half0=[qhi,qlo], half1=[qhi,0])
//  kfrag[bh][jt][half][j&31]  : A-frag for QK  (half0=[khi,khi], half1=[klo,0])
//   -> one 32x32x16 MFMA computes qhi*khi + qlo*khi + qhi*klo  (compensated dot)
//  vfrag[bh][step][vh][col][8]: B-frag for PV, col4 = ones (free l = sum(p))
__global__ __launch_bounds__(256) void qkv_pack(const float* __restrict__ x,
                                                const float* __restrict__ w_qkv,
                                                uint4* __restrict__ qfrag,
                                                uint4* __restrict__ kfrag,
                                                unsigned short* __restrict__ vfrag) {
    int blk = blockIdx.x;        // 16 bh * 16 chunks
    int chunk = blk & 15;
    int bh = blk >> 4;
    int b = bh >> 2, h = bh & 3;
    int i = chunk * 256 + threadIdx.x;

    const float* xb = x + ((size_t)b * 64) * N_POS + i;
    const float* wq = w_qkv + (h * 4) * 64;          // wave-uniform rows
    const float* wk = w_qkv + (16 + h * 4) * 64;
    const float* wv = w_qkv + (32 + h * 4) * 64;

    float aq[4] = {0, 0, 0, 0}, ak[4] = {0, 0, 0, 0}, av[4] = {0, 0, 0, 0};
#pragma unroll 8
    for (int c = 0; c < 64; ++c) {
        float xv = xb[(size_t)c * N_POS];
#pragma unroll
        for (int d = 0; d < 4; ++d) {
            aq[d] = fmaf(wq[d * 64 + c], xv, aq[d]);
            ak[d] = fmaf(wk[d * 64 + c], xv, ak[d]);
            av[d] = fmaf(wv[d * 64 + c], xv, av[d]);
        }
    }

    unsigned int qh[4], ql[4], kh[4], kl[4];
#pragma unroll
    for (int d = 0; d < 4; ++d) {
        float qs = aq[d] * QSCALE;
        qh[d] = bfbits(qs);
        ql[d] = bfbits(qs - bff32(qh[d]));
        kh[d] = bfbits(ak[d]);
        kl[d] = bfbits(ak[d] - bff32(kh[d]));
    }

    int it = i >> 5, il = i & 31;
    size_t base = ((size_t)(bh * 128 + it) * 2) * 32 + il;
    qfrag[base]      = make_uint4(pk2(qh[0], qh[1]), pk2(qh[2], qh[3]),
                                  pk2(ql[0], ql[1]), pk2(ql[2], ql[3]));
    qfrag[base + 32] = make_uint4(pk2(qh[0], qh[1]), pk2(qh[2], qh[3]), 0u, 0u);
    kfrag[base]      = make_uint4(pk2(kh[0], kh[1]), pk2(kh[2], kh[3]),
                                  pk2(kh[0], kh[1]), pk2(kh[2], kh[3]));
    kfrag[base + 32] = make_uint4(pk2(kl[0], kl[1]), pk2(kl[2], kl[3]), 0u, 0u);

    // v transpose-pack: element (j&7) of entry [step=j>>4][vh=(j>>3)&1][col=d]
    int step = i >> 4, vh = (i >> 3) & 1, e = i & 7;
    size_t ventry = ((size_t)(bh * 256 + step) * 2 + vh) * 5;
#pragma unroll
    for (int d = 0; d < 4; ++d)
        vfrag[(ventry + d) * 8 + e] = (unsigned short)bfbits(av[d]);
    if (e == 0)  // ones column -> PV MFMA also produces l = sum_j p
        reinterpret_cast<uint4*>(vfrag)[ventry + 4] =
            make_uint4(0x3F803F80u, 0x3F803F80u, 0x3F803F80u, 0x3F803F80u);
}

// ---------------- K2: MFMA flash attention partials ----------------
// wave = one 32-row i-tile x one j-slice (1024 j). Register-double-buffered
// k/v; stores UNNORMALIZED acc + l (max-free softmax => partials sum linearly).
__global__ __launch_bounds__(256, 4) void attn_mfma(const uint4* __restrict__ qfrag,
                                                    const uint4* __restrict__ kfrag,
                                                    const uint4* __restrict__ vfrag,
                                                    float* __restrict__ pacc,
                                                    float* __restrict__ pl) {
    constexpr int JT = 128 / JS;                 // 32 j-tiles per wave
    int wave = threadIdx.x >> 6;
    int lane = threadIdx.x & 63;
    int half = lane >> 5, c = lane & 31;
    int blk = blockIdx.x;                        // 16 bh * 32 itg * JS
    int js = blk & (JS - 1);
    int itg = (blk >> 2) & 31;
    int bh = blk >> 7;
    int it = itg * 4 + wave;

    uint4 qf_u = qfrag[((size_t)(bh * 128 + it) * 2 + half) * 32 + c];
    bf16x8 qf = __builtin_bit_cast(bf16x8, qf_u);

    const uint4* kp = kfrag + (size_t)bh * 128 * 64 + (size_t)js * JT * 64
                    + (size_t)half * 32 + c;
    int vcol = c < 4 ? c : 4;    // cols >4 read the ones column (result ignored)
    const uint4* vp = vfrag + (size_t)bh * 2560 + (size_t)js * JT * 20
                    + half * 5 + vcol;

    f32x16 acc, zc;
#pragma unroll
    for (int r = 0; r < 16; ++r) { acc[r] = 0.f; zc[r] = 0.f; }

    uint4 kf_c = kp[0];
    uint4 v0_c = vp[0];
    uint4 v1_c = vp[10];

#pragma unroll 2
    for (int jj = 0; jj < JT; ++jj) {
        int jn = (jj + 1) & (JT - 1);            // wrap: harmless reload at tail
        uint4 kf_n = kp[jn * 64];
        uint4 v0_n = vp[(2 * jn) * 10];
        uint4 v1_n = vp[(2 * jn + 1) * 10];

        bf16x8 kf = __builtin_bit_cast(bf16x8, kf_c);
        // S^T tile [j=32 rows, i=32 cols], compensated bf16 dot, log2e folded
        f32x16 s = __builtin_amdgcn_mfma_f32_32x32x16_bf16(kf, qf, zc, 0, 0, 0);
        unsigned int t[8];
#pragma unroll
        for (int eo = 0; eo < 8; ++eo) {
            float plo = fexp2(s[2 * eo]);
            float phi = fexp2(s[2 * eo + 1]);
            unsigned int r_;
            asm("v_cvt_pk_bf16_f32 %0, %1, %2" : "=v"(r_) : "v"(plo), "v"(phi));
            t[eo] = r_;
        }
        // D-layout -> PV A-frag: swap upper half of t[a] with lower half of t[a+2]
        asm("v_permlane32_swap_b32 %0, %1" : "+v"(t[0]), "+v"(t[2]));
        asm("v_permlane32_swap_b32 %0, %1" : "+v"(t[1]), "+v"(t[3]));
        asm("v_permlane32_swap_b32 %0, %1" : "+v"(t[4]), "+v"(t[6]));
        asm("v_permlane32_swap_b32 %0, %1" : "+v"(t[5]), "+v"(t[7]));
        bf16x8 pa0 = __builtin_bit_cast(bf16x8, make_uint4(t[0], t[1], t[2], t[3]));
        bf16x8 pa1 = __builtin_bit_cast(bf16x8, make_uint4(t[4], t[5], t[6], t[7]));
        bf16x8 v0 = __builtin_bit_cast(bf16x8, v0_c);
        bf16x8 v1 = __builtin_bit_cast(bf16x8, v1_c);
        acc = __builtin_amdgcn_mfma_f32_32x32x16_bf16(pa0, v0, acc, 0, 0, 0);
        acc = __builtin_amdgcn_mfma_f32_32x32x16_bf16(pa1, v1, acc, 0, 0, 0);

        kf_c = kf_n; v0_c = v0_n; v1_c = v1_n;
    }

    // store partials: cols 0-3 = sum p*v, col 4 = l = sum p (unnormalized)
    size_t pbase = (size_t)(js * BH + bh) * N_POS + it * 32;
    if (c < 4) {
#pragma unroll
        for (int r = 0; r < 16; ++r) {
            int row = (r & 3) + 8 * (r >> 2) + 4 * half;
            pacc[(pbase + row) * 4 + c] = acc[r];
        }
    } else if (c == 4) {
#pragma unroll
        for (int r = 0; r < 16; ++r) {
            int row = (r & 3) + 8 * (r >> 2) + 4 * half;
            pl[pbase + row] = acc[r];
        }
    }
}

// ---------------- K3: combine partials + output projection + bias -------------
__global__ __launch_bounds__(256) void out_proj(const float4* __restrict__ pacc,
                                                const float* __restrict__ pl,
                                                const float* __restrict__ w_out,
                                                const float* __restrict__ b_out,
                                                float* __restrict__ y) {
    int t = blockIdx.x * 256 + threadIdx.x;
    int b  = t >> 14;
    int cq = (t >> 12) & 3;
    int i  = t & 4095;

    float of[16];
#pragma unroll
    for (int h = 0; h < 4; ++h) {
        int bh = b * 4 + h;
        float sx = 0.f, sy = 0.f, sz = 0.f, sw = 0.f, l = 0.f;
#pragma unroll
        for (int js = 0; js < JS; ++js) {
            size_t idx = (size_t)(js * BH + bh) * N_POS + i;
            float4 a = pacc[idx];
            sx += a.x; sy += a.y; sz += a.z; sw += a.w;
            l += pl[idx];
        }
        float inv = 1.0f / l;
        of[h * 4 + 0] = sx * inv;
        of[h * 4 + 1] = sy * inv;
        of[h * 4 + 2] = sz * inv;
        of[h * 4 + 3] = sw * inv;
    }

    float* yb = y + ((size_t)b * 64 + cq * 16) * N_POS + i;
#pragma unroll
    for (int cc = 0; cc < 16; ++cc) {
        const float* wr = w_out + (cq * 16 + cc) * 16;  // wave-uniform row
        float s = b_out[cq * 16 + cc];
#pragma unroll
        for (int u = 0; u < 16; ++u) s = fmaf(wr[u], of[u], s);
        yb[(size_t)cc * N_POS] = s;
    }
}

extern "C" void kernel_launch(void* const* d_in, const int* in_sizes, int n_in,
                              void* d_out, int out_size, void* d_ws, size_t ws_size,
                              hipStream_t stream) {
    const float* x     = (const float*)d_in[0];
    const float* w_qkv = (const float*)d_in[1];
    const float* w_out = (const float*)d_in[2];
    const float* b_out = (const float*)d_in[3];
    float* y = (float*)d_out;

    // workspace (bytes): qfrag 2MB | kfrag 2MB | vfrag 640KB (pad to 1MB) |
    //                    pacc JS*1MB = 4MB | pl JS*256KB = 1MB   (~10MB)
    char* w = (char*)d_ws;
    uint4*          qfrag = (uint4*)(w);
    uint4*          kfrag = (uint4*)(w + 2097152);
    unsigned short* vfrag = (unsigned short*)(w + 4194304);
    float*          pacc  = (float*)(w + 5242880);
    float*          pl    = (float*)(w + 5242880 + (size_t)JS * 1048576);

    qkv_pack<<<256, 256, 0, stream>>>(x, w_qkv, qfrag, kfrag, vfrag);
    attn_mfma<<<BH * 32 * JS, 256, 0, stream>>>(qfrag, kfrag, (const uint4*)vfrag,
                                                pacc, pl);
    out_proj<<<256, 256, 0, stream>>>((const float4*)pacc, pl, w_out, b_out, y);
}